// Round 3
// 668.847 us; speedup vs baseline: 1.0123x; 1.0123x over previous
//
#include <hip/hip_runtime.h>

// x: (B=64, L=4096, F=256) fp32
// out = [ d : (64, 4095, 256) ][ y : (64, 4095, 256) ]  flat fp32
//   d[b,l,f] = x[b,l+1,f] - x[b,l,f]
//   y[b,l,f] = x[b,l+1,f] - x[b,0,f]   (l < 4094);  y[b,4094,f] = 0
//
// R3 (2nd resubmit; two GPU-broker timeouts, never measured). SWEEP LAYOUT.
// R1/R2's private per-wave 32-row streams (24K concurrent 1KiB-granular
// streams, L2-bypassed) ran at ~2.45 TB/s effective (~332us kernel). The
// two >=6.2 TB/s kernels on this box (rocclr fill, m13 copy) both sweep
// contiguous addresses in dispatch order. This version: one wave = one row,
// consecutive blocks = consecutive rows, so the resident ~2048 blocks form
// 3 dense moving address windows (x-read, d-write, y-write). prev/cur row
// reads overlap between adjacent waves -> plain cached loads, L2/L3 serve
// the second touch (HBM read stays ~1x). Plain stores (= fill's known-good
// write path). Predicted kernel ~130-180us.

typedef float v4f __attribute__((ext_vector_type(4)));

constexpr int B    = 64;
constexpr int L    = 4096;
constexpr int F    = 256;
constexpr int F4   = F / 4;     // 64 float4 per row = exactly one wave
constexpr int LOUT = L - 1;     // 4095 output rows

__global__ __launch_bounds__(256)
void invdiff_kernel(const float* __restrict__ x, float* __restrict__ out) {
    const int lane = threadIdx.x & 63;   // float4 index within row
    const int wave = threadIdx.x >> 6;   // 4 waves per block
    const int b    = blockIdx.y;
    const int l    = blockIdx.x * 4 + wave;   // row index, 0..4095
    if (l >= LOUT) return;               // only block 1023 / wave 3 exits

    const v4f* xb = (const v4f*)(x + (size_t)b * L * F);
    const v4f prev = xb[(size_t)l * F4 + lane];        // x[b, l  ]
    const v4f cur  = xb[(size_t)(l + 1) * F4 + lane];  // x[b, l+1]
    const v4f x0   = xb[lane];                         // x[b, 0] (L3-hot)

    v4f* dout = (v4f*)out + ((size_t)b * LOUT + l) * F4 + lane;
    v4f* yout = dout + (size_t)B * LOUT * F4;

    const v4f zero = {0.f, 0.f, 0.f, 0.f};
    *dout = cur - prev;
    *yout = (l == LOUT - 1) ? zero : cur - x0;
}

extern "C" void kernel_launch(void* const* d_in, const int* in_sizes, int n_in,
                              void* d_out, int out_size, void* d_ws, size_t ws_size,
                              hipStream_t stream) {
    const float* x = (const float*)d_in[0];
    float* out = (float*)d_out;
    // grid: 1024 row-groups (4 rows/block) x 64 batches, 256 threads/block.
    // Dispatch order (x fastest) makes consecutive blocks touch consecutive
    // addresses -> dense moving DRAM windows instead of private streams.
    invdiff_kernel<<<dim3(1024, B), dim3(256), 0, stream>>>(x, out);
}